// Round 8
// baseline (400.308 us; speedup 1.0000x reference)
//
#include <hip/hip_runtime.h>
#include <hip/hip_bf16.h>

// N=50000 nodes, E=800000 edges, D=128, F_IN=8, C=2
// Output float32: [probs E*2 | bbox_pairs E*8 | bbox_index_pairs E*2]

typedef __attribute__((ext_vector_type(8))) short short8;
typedef __attribute__((ext_vector_type(4))) float f32x4;

__device__ inline ushort f2bf(float f) {
    union { __hip_bfloat16 h; ushort u; } cv;
    cv.h = __float2bfloat16(f);
    return cv.u;
}
__device__ inline float bf2f(ushort u) {
    union { float f; uint u; } c;
    c.u = ((uint)u) << 16;
    return c.f;
}

// ---------------- CSR build ----------------
__global__ void k_hist(const int* __restrict__ col, int* __restrict__ cnt, int E) {
    int e = blockIdx.x * blockDim.x + threadIdx.x;
    if (e < E) atomicAdd(&cnt[col[e]], 1);
}

__global__ __launch_bounds__(1024) void k_scan(const int* __restrict__ cnt,
                                               int* __restrict__ ptr, int N) {
    __shared__ int sums[1024];
    int tid = threadIdx.x;
    int chunk = (N + 1023) / 1024;
    int lo = tid * chunk;
    int hi = min(lo + chunk, N);
    int s = 0;
    for (int i = lo; i < hi; ++i) s += cnt[i];
    sums[tid] = s;
    __syncthreads();
    for (int off = 1; off < 1024; off <<= 1) {
        int v = (tid >= off) ? sums[tid - off] : 0;
        __syncthreads();
        sums[tid] += v;
        __syncthreads();
    }
    int run = (tid > 0) ? sums[tid - 1] : 0;
    for (int i = lo; i < hi; ++i) { ptr[i] = run; run += cnt[i]; }
    if (tid == 1023) ptr[N] = run;
}

// fill CSR; dinv computed inline from final cnt (deg = cnt, self-loop adds 1)
__global__ void k_fill(const int* __restrict__ row, const int* __restrict__ col,
                       const int* __restrict__ cnt, const int* __restrict__ ptr,
                       int* __restrict__ cursor, int* __restrict__ esrc,
                       float* __restrict__ enorm, int E) {
    int e = blockIdx.x * blockDim.x + threadIdx.x;
    if (e >= E) return;
    int r = row[e], c = col[e];
    float dr = rsqrtf(1.0f + (float)cnt[r]);
    float dc = rsqrtf(1.0f + (float)cnt[c]);
    int p = ptr[c] + atomicAdd(&cursor[c], 1);
    esrc[p] = r;
    enorm[p] = dr * dc;
}

// ---------------- weight prep ----------------
__global__ void k_prepW(const float* __restrict__ W, ushort* __restrict__ Wt) {
    int tid = blockIdx.x * blockDim.x + threadIdx.x;
    if (tid >= 128 * 256) return;
    int n = tid >> 8, k = tid & 255;
    Wt[tid] = f2bf(W[k * 128 + n]);
}
__global__ void k_prepW2(const float* __restrict__ W, ushort* __restrict__ Wt) {
    int tid = blockIdx.x * blockDim.x + threadIdx.x;
    if (tid >= 128 * 128) return;
    int n = tid >> 7, k = tid & 127;
    Wt[tid] = f2bf(W[k * 128 + n]);
}

// ---------------- layer-1 aggregate on raw features [N,8] ----------------
__global__ __launch_bounds__(256) void k_agg8(const float* __restrict__ feat,
                                              const int* __restrict__ cnt,
                                              const int* __restrict__ ptr,
                                              const int* __restrict__ esrc,
                                              const float* __restrict__ enorm,
                                              float* __restrict__ aggF, int N) {
    int lane8 = threadIdx.x & 7;
    int node = blockIdx.x * 32 + (threadIdx.x >> 3);
    if (node >= N) return;
    float dd = 1.0f / (1.0f + (float)cnt[node]);
    float acc = feat[(size_t)node * 8 + lane8] * dd;
    int i = ptr[node], end = ptr[node + 1];
    for (; i < end; ++i) {
        acc += feat[(size_t)esrc[i] * 8 + lane8] * enorm[i];
    }
    aggF[(size_t)node * 8 + lane8] = acc;
}

// ---------------- layer-1 GEMM: x1 = bf16(relu(aggF[N,8] @ W1 + b1)) ----------------
__global__ __launch_bounds__(256) void k_gemm1(const float* __restrict__ aggF,
                                               const float* __restrict__ W1,
                                               const float* __restrict__ b1,
                                               ushort* __restrict__ x1, int total) {
    int tid = blockIdx.x * blockDim.x + threadIdx.x;
    if (tid >= total) return;
    int n = tid >> 7, j = tid & 127;
    float acc = b1[j];
#pragma unroll
    for (int k = 0; k < 8; ++k) acc += aggF[(size_t)n * 8 + k] * W1[k * 128 + j];
    x1[tid] = f2bf(fmaxf(acc, 0.f));
}

// ---------------- layer-2 GEMM via MFMA: h2 = x1[N,128] @ W2 (bf16 out) ----------------
// Block: 256 thr = 4 waves, 64 nodes. Wave: 16 nodes x 128 cols, K=128.  (R5 shape)
__global__ __launch_bounds__(256) void k_gemm2(const ushort* __restrict__ x1,
                                               const ushort* __restrict__ W2t,
                                               ushort* __restrict__ h2, int N) {
    __shared__ ushort ldsW[128 * 128];   // 32 KB, XOR-swizzled (256B rows)
    const int tid = threadIdx.x;
    const int wave = tid >> 6, lane = tid & 63;
    const int m = lane & 15, kb = lane >> 4;
    const int n0 = blockIdx.x * 64;

    const int node_a = min(n0 + wave * 16 + m, N - 1);
    short8 a[4];
#pragma unroll
    for (int kk = 0; kk < 4; ++kk) {
        a[kk] = *reinterpret_cast<const short8*>(&x1[(size_t)node_a * 128 + kk * 32 + kb * 8]);
    }

    {
        char* lb = reinterpret_cast<char*>(ldsW);
        const short8* wg = reinterpret_cast<const short8*>(W2t);
#pragma unroll
        for (int i = 0; i < 8; ++i) {
            const int g = i * 256 + tid;
            const int bo = g * 16;
            const int swz = bo ^ (((bo >> 8) & 7) << 4);
            *reinterpret_cast<short8*>(lb + swz) = wg[g];
        }
    }
    __syncthreads();

    f32x4 acc[8];
#pragma unroll
    for (int t = 0; t < 8; ++t) acc[t] = (f32x4){0.f, 0.f, 0.f, 0.f};

    const char* lbr = reinterpret_cast<const char*>(ldsW);
    const int mswz = (m & 7) << 4;
#pragma unroll
    for (int kk = 0; kk < 4; ++kk) {
#pragma unroll
        for (int t = 0; t < 8; ++t) {
            const int bo = (t * 16 + m) * 256 + kk * 64 + kb * 16;
            const short8 b = *reinterpret_cast<const short8*>(lbr + (bo ^ mswz));
            acc[t] = __builtin_amdgcn_mfma_f32_16x16x32_bf16(a[kk], b, acc[t], 0, 0, 0);
        }
    }

    // C layout: col = t*16 + m, row(node) = kb*4 + r
#pragma unroll
    for (int r = 0; r < 4; ++r) {
        const int node = n0 + wave * 16 + kb * 4 + r;
        if (node < N) {
#pragma unroll
            for (int t = 0; t < 8; ++t) {
                h2[(size_t)node * 128 + t * 16 + m] = f2bf(acc[t][r]);
            }
        }
    }
}

// ---------------- layer-2 aggregate: one WAVE per node, 4B/lane ----------------
// xbf[node] = bf16(relu(h2[node]*dd + sum_in h2[s]*norm + b2))
__global__ __launch_bounds__(256) void k_gather2(const ushort* __restrict__ h2,
                                                 const int* __restrict__ cnt,
                                                 const int* __restrict__ ptr,
                                                 const int* __restrict__ esrc,
                                                 const float* __restrict__ enorm,
                                                 const float* __restrict__ b2,
                                                 ushort* __restrict__ xbf, int N) {
    const int lane = threadIdx.x & 63;
    const int node = blockIdx.x * 4 + (threadIdx.x >> 6);
    if (node >= N) return;
    const uint* rowp = reinterpret_cast<const uint*>(h2);
    const float dd = 1.0f / (1.0f + (float)cnt[node]);
    uint v = rowp[(size_t)node * 64 + lane];
    float a0 = bf2f((ushort)(v & 0xffffu)) * dd;
    float a1 = bf2f((ushort)(v >> 16)) * dd;
    int i = ptr[node];
    const int end = ptr[node + 1];
    for (; i < end; ++i) {
        const int s = esrc[i];          // wave-uniform -> scalar load
        const float nm = enorm[i];      // wave-uniform
        const uint w = rowp[(size_t)s * 64 + lane];   // one 256B row per wave
        a0 += bf2f((ushort)(w & 0xffffu)) * nm;
        a1 += bf2f((ushort)(w >> 16)) * nm;
    }
    const float2 bb = *reinterpret_cast<const float2*>(&b2[lane * 2]);
    a0 = fmaxf(a0 + bb.x, 0.f);
    a1 = fmaxf(a1 + bb.y, 0.f);
    const uint r = (uint)f2bf(a0) | ((uint)f2bf(a1) << 16);
    reinterpret_cast<uint*>(xbf)[(size_t)node * 64 + lane] = r;
}

// ---------------- edge MLP via MFMA, LDS-staged weights (R5 shape) ----------------
// Block: 512 threads = 8 waves, 128 edges. Wave: 16 edges x 128 hidden, K=256.
#define EB2 128
__global__ __launch_bounds__(512) void k_edge_mfma(const ushort* __restrict__ xbf,
                                                   const ushort* __restrict__ Wt,
                                                   const float* __restrict__ lin1b,
                                                   const float* __restrict__ linfW,
                                                   const float* __restrict__ linfb,
                                                   const float* __restrict__ bboxes,
                                                   const int* __restrict__ bidx,
                                                   const int* __restrict__ row,
                                                   const int* __restrict__ col,
                                                   float* __restrict__ out_probs,
                                                   float* __restrict__ out_bbox,
                                                   float* __restrict__ out_bidx,
                                                   int E) {
    __shared__ ushort ldsW[128 * 256];   // 64 KB, XOR-swizzled (512B rows)
    const int tid = threadIdx.x;
    const int wave = tid >> 6, lane = tid & 63;
    const int e0 = blockIdx.x * EB2;
    const int m = lane & 15;
    const int kb = lane >> 4;

    const int e = e0 + wave * 16 + m;
    const int ec = (e < E) ? e : (E - 1);
    const int src = row[ec], dst = col[ec];

    short8 a[8];
#pragma unroll
    for (int kk = 0; kk < 8; ++kk) {
        const int kloc = kk * 32 + kb * 8;
        const int node = (kloc < 128) ? src : dst;
        a[kk] = *reinterpret_cast<const short8*>(&xbf[(size_t)node * 128 + (kloc & 127)]);
    }

    {
        char* lb = reinterpret_cast<char*>(ldsW);
        const short8* wg = reinterpret_cast<const short8*>(Wt);
#pragma unroll
        for (int i = 0; i < 8; ++i) {
            const int g = i * 512 + tid;
            const int bo = g * 16;
            const int swz = bo ^ (((bo >> 9) & 7) << 4);
            *reinterpret_cast<short8*>(lb + swz) = wg[g];
        }
    }
    __syncthreads();

    f32x4 acc[8];
#pragma unroll
    for (int t = 0; t < 8; ++t) acc[t] = (f32x4){0.f, 0.f, 0.f, 0.f};

    const char* lbr = reinterpret_cast<const char*>(ldsW);
    const int mswz = (m & 7) << 4;
#pragma unroll
    for (int kk = 0; kk < 8; ++kk) {
        const int kloc = kk * 32 + kb * 8;
#pragma unroll
        for (int t = 0; t < 8; ++t) {
            const int bo = ((t * 16 + m) * 256 + kloc) * 2;
            const short8 b = *reinterpret_cast<const short8*>(lbr + (bo ^ mswz));
            acc[t] = __builtin_amdgcn_mfma_f32_16x16x32_bf16(a[kk], b, acc[t], 0, 0, 0);
        }
    }

    float p0[4] = {0.f, 0.f, 0.f, 0.f};
    float p1[4] = {0.f, 0.f, 0.f, 0.f};
#pragma unroll
    for (int t = 0; t < 8; ++t) {
        const int n = t * 16 + m;
        const float bn = lin1b[n];
        const float2 wf = *reinterpret_cast<const float2*>(&linfW[n * 2]);
#pragma unroll
        for (int r = 0; r < 4; ++r) {
            const float hv = fmaxf(acc[t][r] + bn, 0.f);
            p0[r] += hv * wf.x;
            p1[r] += hv * wf.y;
        }
    }
#pragma unroll
    for (int s = 1; s < 16; s <<= 1) {
#pragma unroll
        for (int r = 0; r < 4; ++r) {
            p0[r] += __shfl_xor(p0[r], s);
            p1[r] += __shfl_xor(p1[r], s);
        }
    }
    if (m < 4) {
        const int er = e0 + wave * 16 + (kb << 2) + m;
        if (er < E) {
            const float z0 = p0[m] + linfb[0];
            const float z1 = p1[m] + linfb[1];
            const float mx = fmaxf(z0, z1);
            const float lse = mx + logf(expf(z0 - mx) + expf(z1 - mx));
            *reinterpret_cast<float2*>(&out_probs[(size_t)er * 2]) = make_float2(z0 - lse, z1 - lse);
        }
    }

    for (int idx = tid; idx < EB2 * 8; idx += 512) {
        const int ee = idx >> 3, q = idx & 7;
        const int e2 = e0 + ee;
        if (e2 < E) {
            const int node = (q < 4) ? row[e2] : col[e2];
            out_bbox[(size_t)e2 * 8 + q] = bboxes[(size_t)node * 4 + (q & 3)];
        }
    }
    for (int idx = tid; idx < EB2 * 2; idx += 512) {
        const int ee = idx >> 1, c = idx & 1;
        const int e2 = e0 + ee;
        if (e2 < E) {
            const int node = c ? col[e2] : row[e2];
            out_bidx[(size_t)e2 * 2 + c] = (float)bidx[node];
        }
    }
}

extern "C" void kernel_launch(void* const* d_in, const int* in_sizes, int n_in,
                              void* d_out, int out_size, void* d_ws, size_t ws_size,
                              hipStream_t stream) {
    const float* feat   = (const float*)d_in[0];
    const float* bboxes = (const float*)d_in[1];
    const int*   bidx   = (const int*)d_in[2];
    const int*   eidx   = (const int*)d_in[3];
    const float* W1     = (const float*)d_in[4];
    const float* b1     = (const float*)d_in[5];
    const float* W2     = (const float*)d_in[6];
    const float* b2     = (const float*)d_in[7];
    const float* lin1W  = (const float*)d_in[8];
    const float* lin1b  = (const float*)d_in[9];
    const float* linfW  = (const float*)d_in[10];
    const float* linfb  = (const float*)d_in[11];

    const int N = in_sizes[0] / 8;
    const int E = in_sizes[3] / 2;
    const int* row = eidx;        // sources
    const int* col = eidx + E;    // targets

    size_t Np = ((size_t)N + 255) & ~255ull;
    size_t Ep = ((size_t)E + 255) & ~255ull;
    size_t A8 = (((size_t)N * 8) + 255) & ~255ull;
    int*    cnt    = (int*)d_ws;                 // Np
    int*    cursor = cnt + Np;                   // Np (zeroed together with cnt)
    int*    ptr    = cursor + Np;                // Np+256
    int*    esrc   = ptr + Np + 256;             // Ep
    float*  enorm  = (float*)(esrc + Ep);        // Ep
    float*  aggF   = enorm + Ep;                 // A8 f32
    ushort* x1     = (ushort*)(aggF + A8);       // N*128 bf16
    ushort* h2     = x1 + (size_t)N * 128;       // N*128 bf16
    ushort* xbf    = h2 + (size_t)N * 128;       // N*128 bf16
    ushort* Wt     = xbf + (size_t)N * 128;      // 128*256 bf16
    ushort* W2t    = Wt + 128 * 256;             // 128*128 bf16

    float* out       = (float*)d_out;
    float* out_probs = out;                   // E*2
    float* out_bbox  = out + (size_t)E * 2;   // E*8
    float* out_bidx  = out + (size_t)E * 10;  // E*2

    const int total = N * 128;
    const int B = 256;

    // CSR build + weight prep
    hipMemsetAsync(cnt, 0, 2 * Np * sizeof(int), stream);   // cnt + cursor
    k_hist<<<(E + B - 1) / B, B, 0, stream>>>(col, cnt, E);
    k_scan<<<1, 1024, 0, stream>>>(cnt, ptr, N);
    k_fill<<<(E + B - 1) / B, B, 0, stream>>>(row, col, cnt, ptr, cursor, esrc, enorm, E);
    k_prepW<<<(128 * 256 + B - 1) / B, B, 0, stream>>>(lin1W, Wt);
    k_prepW2<<<(128 * 128 + B - 1) / B, B, 0, stream>>>(W2, W2t);

    // layer 1 (aggregate-first on [N,8], then tiny GEMM)
    k_agg8<<<(N + 31) / 32, B, 0, stream>>>(feat, cnt, ptr, esrc, enorm, aggF, N);
    k_gemm1<<<(total + B - 1) / B, B, 0, stream>>>(aggF, W1, b1, x1, total);

    // layer 2 (MFMA GEMM, then wave-per-node gather)
    k_gemm2<<<(N + 63) / 64, B, 0, stream>>>(x1, W2t, h2, N);
    k_gather2<<<(N + 3) / 4, B, 0, stream>>>(h2, cnt, ptr, esrc, enorm, b2, xbf, N);

    // edge MLP (MFMA, LDS weights) + outputs
    k_edge_mfma<<<(E + EB2 - 1) / EB2, 512, 0, stream>>>(xbf, Wt, lin1b, linfW, linfb,
                                                         bboxes, bidx, row, col,
                                                         out_probs, out_bbox, out_bidx, E);
}